// Round 10
// baseline (826.041 us; speedup 1.0000x reference)
//
#include <hip/hip_runtime.h>

typedef _Float16 f16;
typedef __attribute__((ext_vector_type(8))) _Float16 f16x8;
typedef __attribute__((ext_vector_type(4))) _Float16 f16x4;
typedef __attribute__((ext_vector_type(4))) float f32x4;

#define BATCH 16
#define NSEQ  2048
#define DDIM  300
#define DPK   328   // padded row length (f16) for row-major Xf/Yf (zeros in [300,328))
#define DPV   304   // padded d-rows for transposed XT/YT (zeros in [300,304))
#define NTP   2056  // padded q-cols for transposed copies (zeros in [2048,2056))
#define XF_ELEMS (BATCH*NSEQ*DPK)
#define XT_ELEMS (BATCH*DPV*NTP)

__device__ __forceinline__ void gl_lds16(const void* g, void* l) {
  __builtin_amdgcn_global_load_lds((const __attribute__((address_space(1))) unsigned int*)g,
                                   (__attribute__((address_space(3))) unsigned int*)l, 16, 0, 0);
}

// ---------------------------------------------------------------------------
// Preprocess: X,Y f32 -> f16 row-major (padded) + f16 transposed (padded)
// ---------------------------------------------------------------------------
__global__ __launch_bounds__(256) void prep_kernel(const float* __restrict__ X,
                                                   const float* __restrict__ Y,
                                                   f16* __restrict__ Xf, f16* __restrict__ Yf,
                                                   f16* __restrict__ XT, f16* __restrict__ YT) {
  __shared__ float tile[32][33];
  int bz   = blockIdx.z;            // 0..31 = tensor*16 + b
  int tsel = bz >> 4, b = bz & 15;
  const float* src = tsel ? Y : X;
  f16* dF = tsel ? Yf : Xf;
  f16* dT = tsel ? YT : XT;
  int d0 = blockIdx.y * 32;
  int q0 = blockIdx.x * 32;
  int tid = threadIdx.x;
  int c = tid & 31, rr = tid >> 5;

  #pragma unroll
  for (int i = 0; i < 4; ++i) {
    int qr = rr + i * 8;
    int q = q0 + qr, d = d0 + c;
    float v = 0.f;
    if (q < NSEQ && d < DDIM) v = src[(size_t)b * NSEQ * DDIM + (size_t)q * DDIM + d];
    tile[c][qr] = v;
    if (q < NSEQ && d < DPK) dF[(size_t)b * NSEQ * DPK + (size_t)q * DPK + d] = (f16)v;
  }
  __syncthreads();
  #pragma unroll
  for (int i = 0; i < 4; ++i) {
    int dr = rr + i * 8;
    int d = d0 + dr, q = q0 + c;
    if (d < DPV && q < NTP) dT[(size_t)b * DPV * NTP + (size_t)d * NTP + q] = (f16)tile[dr][c];
  }
}

// ---------------------------------------------------------------------------
// Flash attention v10: R9's pipelined 2-barrier schedule with SINGLE-buffered
// K and V so that per-block LDS = 56 KB and TWO 512-thread blocks co-reside
// per CU (combined <= 128 KB law: R1 2x50.7K yes / R4 2x72.2K no).
// 8 waves = 4 qg x 2 members, QBLK=128, KV tile 32.
// Iter t: phase1 {PV[t-1] + QK^T[t]} -> shfl max -> B1 (all phase-1 reads of
// K[t]/V[t-1]/P[t-1] complete => single-buffer staging is race-free) ->
// stage K[t+1],V[t] -> exp/P-write/rescale -> B2 (lgkm + vmcnt(0)).
// PV trails one tile; epilogue does PV[63].
// __launch_bounds__(512,4): VGPR cap 128 (need 108, R9) -> 4 waves/SIMD ok.
// Grid 512 = exactly 2 blocks/CU, XCD-chunk swizzled.
// ---------------------------------------------------------------------------
__global__ __launch_bounds__(512, 4) void attn_kernel(const f16* __restrict__ Xf,
                                                      const f16* __restrict__ Yf,
                                                      const f16* __restrict__ XT,
                                                      const f16* __restrict__ YT,
                                                      float* __restrict__ out) {
  __shared__ __align__(16) f16 Ksh[32][DPK];      // 20992 B (656 B rows)
  __shared__ __align__(16) f16 VTsh[DPV][40];     // 24320 B (80 B rows)
  __shared__ __align__(16) f16 Psh[4][32][40];    // 10240 B per-qg P
  __shared__ float2 Mx[4][2][16];                 //   512 B max/lsum exchange
                                                  // total 56064 B -> 2 blocks/CU

  int idx = blockIdx.x;
  int swz = (idx & 7) * 64 + (idx >> 3);          // 512 % 8 == 0: bijective XCD chunking
  int qt  = swz & 15;
  int b   = (swz >> 4) & 15;
  int dir = swz >> 8;

  const f16* Qsrc = dir ? Yf : Xf;
  const f16* Ksrc = dir ? Xf : Yf;
  const f16* Vts  = dir ? XT : YT;   // V^T source [DPV][NTP]

  const size_t bq = (size_t)b * NSEQ * DPK;
  const size_t bt = (size_t)b * DPV * NTP;

  int tid = threadIdx.x;
  int lane = tid & 63, wid = tid >> 6;
  int qg = wid >> 1, mem = wid & 1;
  int l15 = lane & 15, g = lane >> 4;
  int qbase = qt * 128 + qg * 32;     // q-group's 32 rows (shared by both members)

  // Q fragments (both members hold qg's 32 q): lane = Q[q=qi*16+l15][ks*32+g*8+j]
  f16x8 qf[2][10];
  #pragma unroll
  for (int qi = 0; qi < 2; ++qi) {
    const f16* qrow = Qsrc + bq + (size_t)(qbase + qi * 16 + l15) * DPK + g * 8;
    #pragma unroll
    for (int ks = 0; ks < 10; ++ks) qf[qi][ks] = *(const f16x8*)(qrow + ks * 32);
  }

  const int dtoff = mem ? 10 : 0;     // PV d-tiles: member0 d 0..159, member1 160..303
  const int ndt   = mem ? 9 : 10;

  f32x4 O[10][2];
  #pragma unroll
  for (int dt = 0; dt < 10; ++dt) {
    O[dt][0] = (f32x4){0.f, 0.f, 0.f, 0.f};
    O[dt][1] = (f32x4){0.f, 0.f, 0.f, 0.f};
  }
  float m0 = -3.0e38f, m1 = -3.0e38f, l0 = 0.f, l1 = 0.f;

  const char* gK0 = (const char*)(Ksrc + bq);
  const char* gV0 = (const char*)(Vts + bt);

  auto stageK = [&](int tt) {
    const char* gK = gK0 + (size_t)tt * (32 * DPK * 2);
    char* lK = (char*)&Ksh[0][0];
    #pragma unroll
    for (int i = 0; i < 3; ++i) {          // 1312 chunks of 16 B
      int c = i * 512 + tid;
      if (c < 1312) gl_lds16(gK + c * 16, lK + c * 16);
    }
  };
  auto stageV = [&](int tt) {
    const char* gV = gV0 + (size_t)tt * 64;
    char* lV = (char*)&VTsh[0][0];
    #pragma unroll
    for (int i = 0; i < 3; ++i) {          // 304 rows x 5 slots (64 B data + 16 B pad read)
      int c = i * 512 + tid;
      if (c < 1520) {
        int row = c / 5, slot = c - row * 5;
        gl_lds16(gV + (size_t)row * (NTP * 2) + slot * 16, lV + c * 16);
      }
    }
  };

  stageK(0);                                // K[0]
  asm volatile("s_waitcnt vmcnt(0)" ::: "memory");
  __builtin_amdgcn_s_barrier();
  __builtin_amdgcn_sched_barrier(0);

  #pragma unroll 1
  for (int t = 0; t < 64; ++t) {
    // ---- Phase 1: merged MFMA cluster — PV[t-1] (from single V/P bufs) + QK^T[t]
    f32x4 S0 = (f32x4){0.f,0.f,0.f,0.f}, S1 = (f32x4){0.f,0.f,0.f,0.f};
    __builtin_amdgcn_s_setprio(1);
    if (t > 0) {
      f16x8 pb0 = *(const f16x8*)&Psh[qg][l15][g * 8];
      f16x8 pb1 = *(const f16x8*)&Psh[qg][16 + l15][g * 8];
      #pragma unroll
      for (int dt = 0; dt < 10; ++dt) {
        if (dt < ndt) {
          f16x8 vf = *(const f16x8*)&VTsh[(dtoff + dt) * 16 + l15][g * 8];
          O[dt][0] = __builtin_amdgcn_mfma_f32_16x16x32_f16(vf, pb0, O[dt][0], 0, 0, 0);
          O[dt][1] = __builtin_amdgcn_mfma_f32_16x16x32_f16(vf, pb1, O[dt][1], 0, 0, 0);
        }
      }
    }
    #pragma unroll
    for (int ks = 0; ks < 10; ++ks) {
      f16x8 a = *(const f16x8*)&Ksh[mem * 16 + l15][ks * 32 + g * 8];
      S0 = __builtin_amdgcn_mfma_f32_16x16x32_f16(a, qf[0][ks], S0, 0, 0, 0);
      S1 = __builtin_amdgcn_mfma_f32_16x16x32_f16(a, qf[1][ks], S1, 0, 0, 0);
    }
    __builtin_amdgcn_s_setprio(0);

    // ---- Phase 2: partial max over own 16 kv (per q-col = l15, per qi)
    float p0 = fmaxf(fmaxf(S0[0], S0[1]), fmaxf(S0[2], S0[3]));
    float p1 = fmaxf(fmaxf(S1[0], S1[1]), fmaxf(S1[2], S1[3]));
    p0 = fmaxf(p0, __shfl_xor(p0, 16, 64)); p0 = fmaxf(p0, __shfl_xor(p0, 32, 64));
    p1 = fmaxf(p1, __shfl_xor(p1, 16, 64)); p1 = fmaxf(p1, __shfl_xor(p1, 32, 64));
    if (g == 0) Mx[qg][mem][l15] = float2{p0, p1};

    // ---- B1: max exchange visible; ALL waves past phase-1 reads of
    //      K[t], V[t-1], P[t-1] -> single-buffer staging below is race-free.
    asm volatile("s_waitcnt lgkmcnt(0)" ::: "memory");
    __builtin_amdgcn_s_barrier();
    __builtin_amdgcn_sched_barrier(0);

    // ---- Phase 3: stage K[t+1] and V[t] into the (single) buffers.
    if (t < 63) stageK(t + 1);
    stageV(t);

    // ---- Phase 4: combine maxes, defer-max rescale, exp, P-write, sums
    float2 pp = Mx[qg][mem ^ 1][l15];
    float tm0 = fmaxf(p0, pp.x), tm1 = fmaxf(p1, pp.y);

    if (__any(tm0 > m0 + 8.0f)) {          // defer-max (identical in both members)
      float mn = fmaxf(m0, tm0), al = __expf(m0 - mn);
      l0 *= al;
      #pragma unroll
      for (int dt = 0; dt < 10; ++dt) {
        O[dt][0][0] *= al; O[dt][0][1] *= al; O[dt][0][2] *= al; O[dt][0][3] *= al;
      }
      m0 = mn;
    }
    if (__any(tm1 > m1 + 8.0f)) {
      float mn = fmaxf(m1, tm1), al = __expf(m1 - mn);
      l1 *= al;
      #pragma unroll
      for (int dt = 0; dt < 10; ++dt) {
        O[dt][1][0] *= al; O[dt][1][1] *= al; O[dt][1][2] *= al; O[dt][1][3] *= al;
      }
      m1 = mn;
    }

    float ts0 = 0.f, ts1 = 0.f;
    f16x4 h0, h1;
    #pragma unroll
    for (int r = 0; r < 4; ++r) {
      float e0 = __expf(S0[r] - m0);       // bounded by e^8
      float e1 = __expf(S1[r] - m1);
      h0[r] = (f16)e0; h1[r] = (f16)e1;
      ts0 += e0; ts1 += e1;
    }
    *(f16x4*)&Psh[qg][l15][mem * 16 + g * 4]      = h0;   // qi=0 rows
    *(f16x4*)&Psh[qg][16 + l15][mem * 16 + g * 4] = h1;   // qi=1 rows
    ts0 += __shfl_xor(ts0, 16, 64); ts0 += __shfl_xor(ts0, 32, 64);
    ts1 += __shfl_xor(ts1, 16, 64); ts1 += __shfl_xor(ts1, 32, 64);
    l0 += ts0; l1 += ts1;

    // ---- B2: P[t] visible + drain K[t+1],V[t] staging (issued in phase 3)
    asm volatile("s_waitcnt lgkmcnt(0) vmcnt(0)" ::: "memory");
    __builtin_amdgcn_s_barrier();
    __builtin_amdgcn_sched_barrier(0);
  }

  // ---- Epilogue PV[63] (trailing tile of the pipeline)
  {
    f16x8 pb0 = *(const f16x8*)&Psh[qg][l15][g * 8];
    f16x8 pb1 = *(const f16x8*)&Psh[qg][16 + l15][g * 8];
    __builtin_amdgcn_s_setprio(1);
    #pragma unroll
    for (int dt = 0; dt < 10; ++dt) {
      if (dt < ndt) {
        f16x8 vf = *(const f16x8*)&VTsh[(dtoff + dt) * 16 + l15][g * 8];
        O[dt][0] = __builtin_amdgcn_mfma_f32_16x16x32_f16(vf, pb0, O[dt][0], 0, 0, 0);
        O[dt][1] = __builtin_amdgcn_mfma_f32_16x16x32_f16(vf, pb1, O[dt][1], 0, 0, 0);
      }
    }
    __builtin_amdgcn_s_setprio(0);
  }

  // ---- combine pair half-sums, multiply by input row, store
  if (g == 0) Mx[qg][mem][l15] = float2{l0, l1};
  asm volatile("s_waitcnt lgkmcnt(0)" ::: "memory");
  __builtin_amdgcn_s_barrier();
  __builtin_amdgcn_sched_barrier(0);
  float2 pl = Mx[qg][mem ^ 1][l15];
  float r0 = 1.0f / (l0 + pl.x);
  float r1 = 1.0f / (l1 + pl.y);

  #pragma unroll
  for (int qi = 0; qi < 2; ++qi) {
    float rinv = qi ? r1 : r0;
    int q = qbase + qi * 16 + l15;
    const f16* mrow = Qsrc + bq + (size_t)q * DPK;
    size_t orow = (size_t)b * (4096 * 300) + (size_t)(dir * 2048 + q) * 300;
    #pragma unroll
    for (int dt = 0; dt < 10; ++dt) {
      if (dt < ndt) {
        int d = (dtoff + dt) * 16 + g * 4;
        if (d < 300) {
          f16x4 mu = *(const f16x4*)(mrow + d);
          f32x4 o;
          o[0] = O[dt][qi][0] * rinv * (float)mu[0];
          o[1] = O[dt][qi][1] * rinv * (float)mu[1];
          o[2] = O[dt][qi][2] * rinv * (float)mu[2];
          o[3] = O[dt][qi][3] * rinv * (float)mu[3];
          *(f32x4*)&out[orow + d] = o;
        }
      }
    }
  }
}

extern "C" void kernel_launch(void* const* d_in, const int* in_sizes, int n_in,
                              void* d_out, int out_size, void* d_ws, size_t ws_size,
                              hipStream_t stream) {
  const float* X = (const float*)d_in[0];
  const float* Y = (const float*)d_in[1];
  float* out = (float*)d_out;

  size_t need = (size_t)(2 * XF_ELEMS + 2 * XT_ELEMS) * sizeof(f16);  // ~83 MB
  if (ws_size < need) return;

  f16* Xf = (f16*)d_ws;
  f16* Yf = Xf + XF_ELEMS;
  f16* XT = Yf + XF_ELEMS;
  f16* YT = XT + XT_ELEMS;

  prep_kernel<<<dim3(65, 11, 32), 256, 0, stream>>>(X, Y, Xf, Yf, XT, YT);
  attn_kernel<<<dim3(512), 512, 0, stream>>>(Xf, Yf, XT, YT, out);
}

// Round 11
// 312.033 us; speedup vs baseline: 2.6473x; 2.6473x over previous
//
#include <hip/hip_runtime.h>

typedef _Float16 f16;
typedef __attribute__((ext_vector_type(8))) _Float16 f16x8;
typedef __attribute__((ext_vector_type(4))) _Float16 f16x4;
typedef __attribute__((ext_vector_type(4))) float f32x4;

#define BATCH 16
#define NSEQ  2048
#define DDIM  300
#define DPK   328   // padded row length (f16) for row-major Xf/Yf (zeros in [300,328))
#define DPV   304   // padded d-rows for transposed XT/YT (zeros in [300,304))
#define NTP   2056  // padded q-cols for transposed copies (zeros in [2048,2056))
#define XF_ELEMS (BATCH*NSEQ*DPK)
#define XT_ELEMS (BATCH*DPV*NTP)

__device__ __forceinline__ void gl_lds16(const void* g, void* l) {
  __builtin_amdgcn_global_load_lds((const __attribute__((address_space(1))) unsigned int*)g,
                                   (__attribute__((address_space(3))) unsigned int*)l, 16, 0, 0);
}

// ---------------------------------------------------------------------------
// Preprocess: X,Y f32 -> f16 row-major (padded) + f16 transposed (padded)
// ---------------------------------------------------------------------------
__global__ __launch_bounds__(256) void prep_kernel(const float* __restrict__ X,
                                                   const float* __restrict__ Y,
                                                   f16* __restrict__ Xf, f16* __restrict__ Yf,
                                                   f16* __restrict__ XT, f16* __restrict__ YT) {
  __shared__ float tile[32][33];
  int bz   = blockIdx.z;            // 0..31 = tensor*16 + b
  int tsel = bz >> 4, b = bz & 15;
  const float* src = tsel ? Y : X;
  f16* dF = tsel ? Yf : Xf;
  f16* dT = tsel ? YT : XT;
  int d0 = blockIdx.y * 32;
  int q0 = blockIdx.x * 32;
  int tid = threadIdx.x;
  int c = tid & 31, rr = tid >> 5;

  #pragma unroll
  for (int i = 0; i < 4; ++i) {
    int qr = rr + i * 8;
    int q = q0 + qr, d = d0 + c;
    float v = 0.f;
    if (q < NSEQ && d < DDIM) v = src[(size_t)b * NSEQ * DDIM + (size_t)q * DDIM + d];
    tile[c][qr] = v;
    if (q < NSEQ && d < DPK) dF[(size_t)b * NSEQ * DPK + (size_t)q * DPK + d] = (f16)v;
  }
  __syncthreads();
  #pragma unroll
  for (int i = 0; i < 4; ++i) {
    int dr = rr + i * 8;
    int d = d0 + dr, q = q0 + c;
    if (d < DPV && q < NTP) dT[(size_t)b * DPV * NTP + (size_t)d * NTP + q] = (f16)tile[dr][c];
  }
}

// ---------------------------------------------------------------------------
// Flash attention v11 = v10's single-buffered 2-barrier pipeline with the
// allocator left ALONE: __launch_bounds__(512, 1).
// Compiler law (5 probes): min-waves >= 4 (or any 1024-thr block) makes the
// gfx950 allocator target 8 waves/EU -> VGPR=64 -> total spill. At (512,1)
// the natural allocation is 108 VGPR (R5/R9) -> 4 waves/SIMD fit in HW
// (4x108=432<=512), and LDS 56.8 KB -> 2 blocks/CU fit (113.7 <= 128 KB).
// Residency is resource-driven; no hint needed.
// Structure: 8 waves = 4 qg x 2 members, QBLK=128, KV tile 32; kv-split
// QK^T + d-split PV; PV trails one tile, merged into QK^T's MFMA cluster.
// Iter t: {PV[t-1]+QK^T[t]} -> shfl max -> B1 -> stage K[t+1],V[t] (single
// buffers, race-free after B1) -> exp/P/rescale -> B2 (lgkm+vmcnt(0)).
// Grid 512 = 2 blocks/CU, XCD-chunk swizzled.
// ---------------------------------------------------------------------------
__global__ __launch_bounds__(512, 1) void attn_kernel(const f16* __restrict__ Xf,
                                                      const f16* __restrict__ Yf,
                                                      const f16* __restrict__ XT,
                                                      const f16* __restrict__ YT,
                                                      float* __restrict__ out) {
  __shared__ __align__(16) f16 Ksh[32][DPK];      // 20992 B (656 B rows)
  __shared__ __align__(16) f16 VTsh[DPV][40];     // 24320 B (80 B rows)
  __shared__ __align__(16) f16 Psh[4][32][40];    // 10240 B per-qg P
  __shared__ float2 Mx[4][2][16];                 //   512 B max/lsum exchange
                                                  // total 56064 B -> 2 blocks/CU

  int idx = blockIdx.x;
  int swz = (idx & 7) * 64 + (idx >> 3);          // 512 % 8 == 0: bijective XCD chunking
  int qt  = swz & 15;
  int b   = (swz >> 4) & 15;
  int dir = swz >> 8;

  const f16* Qsrc = dir ? Yf : Xf;
  const f16* Ksrc = dir ? Xf : Yf;
  const f16* Vts  = dir ? XT : YT;   // V^T source [DPV][NTP]

  const size_t bq = (size_t)b * NSEQ * DPK;
  const size_t bt = (size_t)b * DPV * NTP;

  int tid = threadIdx.x;
  int lane = tid & 63, wid = tid >> 6;
  int qg = wid >> 1, mem = wid & 1;
  int l15 = lane & 15, g = lane >> 4;
  int qbase = qt * 128 + qg * 32;     // q-group's 32 rows (shared by both members)

  // Q fragments (both members hold qg's 32 q): lane = Q[q=qi*16+l15][ks*32+g*8+j]
  f16x8 qf[2][10];
  #pragma unroll
  for (int qi = 0; qi < 2; ++qi) {
    const f16* qrow = Qsrc + bq + (size_t)(qbase + qi * 16 + l15) * DPK + g * 8;
    #pragma unroll
    for (int ks = 0; ks < 10; ++ks) qf[qi][ks] = *(const f16x8*)(qrow + ks * 32);
  }

  const int dtoff = mem ? 10 : 0;     // PV d-tiles: member0 d 0..159, member1 160..303
  const int ndt   = mem ? 9 : 10;

  f32x4 O[10][2];
  #pragma unroll
  for (int dt = 0; dt < 10; ++dt) {
    O[dt][0] = (f32x4){0.f, 0.f, 0.f, 0.f};
    O[dt][1] = (f32x4){0.f, 0.f, 0.f, 0.f};
  }
  float m0 = -3.0e38f, m1 = -3.0e38f, l0 = 0.f, l1 = 0.f;

  const char* gK0 = (const char*)(Ksrc + bq);
  const char* gV0 = (const char*)(Vts + bt);

  auto stageK = [&](int tt) {
    const char* gK = gK0 + (size_t)tt * (32 * DPK * 2);
    char* lK = (char*)&Ksh[0][0];
    #pragma unroll
    for (int i = 0; i < 3; ++i) {          // 1312 chunks of 16 B
      int c = i * 512 + tid;
      if (c < 1312) gl_lds16(gK + c * 16, lK + c * 16);
    }
  };
  auto stageV = [&](int tt) {
    const char* gV = gV0 + (size_t)tt * 64;
    char* lV = (char*)&VTsh[0][0];
    #pragma unroll
    for (int i = 0; i < 3; ++i) {          // 304 rows x 5 slots (64 B data + 16 B pad read)
      int c = i * 512 + tid;
      if (c < 1520) {
        int row = c / 5, slot = c - row * 5;
        gl_lds16(gV + (size_t)row * (NTP * 2) + slot * 16, lV + c * 16);
      }
    }
  };

  stageK(0);                                // K[0]
  asm volatile("s_waitcnt vmcnt(0)" ::: "memory");
  __builtin_amdgcn_s_barrier();
  __builtin_amdgcn_sched_barrier(0);

  #pragma unroll 1
  for (int t = 0; t < 64; ++t) {
    // ---- Phase 1: merged MFMA cluster — PV[t-1] (single V/P bufs) + QK^T[t]
    f32x4 S0 = (f32x4){0.f,0.f,0.f,0.f}, S1 = (f32x4){0.f,0.f,0.f,0.f};
    __builtin_amdgcn_s_setprio(1);
    if (t > 0) {
      f16x8 pb0 = *(const f16x8*)&Psh[qg][l15][g * 8];
      f16x8 pb1 = *(const f16x8*)&Psh[qg][16 + l15][g * 8];
      #pragma unroll
      for (int dt = 0; dt < 10; ++dt) {
        if (dt < ndt) {
          f16x8 vf = *(const f16x8*)&VTsh[(dtoff + dt) * 16 + l15][g * 8];
          O[dt][0] = __builtin_amdgcn_mfma_f32_16x16x32_f16(vf, pb0, O[dt][0], 0, 0, 0);
          O[dt][1] = __builtin_amdgcn_mfma_f32_16x16x32_f16(vf, pb1, O[dt][1], 0, 0, 0);
        }
      }
    }
    #pragma unroll
    for (int ks = 0; ks < 10; ++ks) {
      f16x8 a = *(const f16x8*)&Ksh[mem * 16 + l15][ks * 32 + g * 8];
      S0 = __builtin_amdgcn_mfma_f32_16x16x32_f16(a, qf[0][ks], S0, 0, 0, 0);
      S1 = __builtin_amdgcn_mfma_f32_16x16x32_f16(a, qf[1][ks], S1, 0, 0, 0);
    }
    __builtin_amdgcn_s_setprio(0);

    // ---- Phase 2: partial max over own 16 kv (per q-col = l15, per qi)
    float p0 = fmaxf(fmaxf(S0[0], S0[1]), fmaxf(S0[2], S0[3]));
    float p1 = fmaxf(fmaxf(S1[0], S1[1]), fmaxf(S1[2], S1[3]));
    p0 = fmaxf(p0, __shfl_xor(p0, 16, 64)); p0 = fmaxf(p0, __shfl_xor(p0, 32, 64));
    p1 = fmaxf(p1, __shfl_xor(p1, 16, 64)); p1 = fmaxf(p1, __shfl_xor(p1, 32, 64));
    if (g == 0) Mx[qg][mem][l15] = float2{p0, p1};

    // ---- B1: max exchange visible; ALL waves past phase-1 reads of
    //      K[t], V[t-1], P[t-1] -> single-buffer staging below is race-free.
    asm volatile("s_waitcnt lgkmcnt(0)" ::: "memory");
    __builtin_amdgcn_s_barrier();
    __builtin_amdgcn_sched_barrier(0);

    // ---- Phase 3: stage K[t+1] and V[t] into the (single) buffers.
    if (t < 63) stageK(t + 1);
    stageV(t);

    // ---- Phase 4: combine maxes, defer-max rescale, exp, P-write, sums
    float2 pp = Mx[qg][mem ^ 1][l15];
    float tm0 = fmaxf(p0, pp.x), tm1 = fmaxf(p1, pp.y);

    if (__any(tm0 > m0 + 8.0f)) {          // defer-max (identical in both members)
      float mn = fmaxf(m0, tm0), al = __expf(m0 - mn);
      l0 *= al;
      #pragma unroll
      for (int dt = 0; dt < 10; ++dt) {
        O[dt][0][0] *= al; O[dt][0][1] *= al; O[dt][0][2] *= al; O[dt][0][3] *= al;
      }
      m0 = mn;
    }
    if (__any(tm1 > m1 + 8.0f)) {
      float mn = fmaxf(m1, tm1), al = __expf(m1 - mn);
      l1 *= al;
      #pragma unroll
      for (int dt = 0; dt < 10; ++dt) {
        O[dt][1][0] *= al; O[dt][1][1] *= al; O[dt][1][2] *= al; O[dt][1][3] *= al;
      }
      m1 = mn;
    }

    float ts0 = 0.f, ts1 = 0.f;
    f16x4 h0, h1;
    #pragma unroll
    for (int r = 0; r < 4; ++r) {
      float e0 = __expf(S0[r] - m0);       // bounded by e^8
      float e1 = __expf(S1[r] - m1);
      h0[r] = (f16)e0; h1[r] = (f16)e1;
      ts0 += e0; ts1 += e1;
    }
    *(f16x4*)&Psh[qg][l15][mem * 16 + g * 4]      = h0;   // qi=0 rows
    *(f16x4*)&Psh[qg][16 + l15][mem * 16 + g * 4] = h1;   // qi=1 rows
    ts0 += __shfl_xor(ts0, 16, 64); ts0 += __shfl_xor(ts0, 32, 64);
    ts1 += __shfl_xor(ts1, 16, 64); ts1 += __shfl_xor(ts1, 32, 64);
    l0 += ts0; l1 += ts1;

    // ---- B2: P[t] visible + drain K[t+1],V[t] staging (issued in phase 3)
    asm volatile("s_waitcnt lgkmcnt(0) vmcnt(0)" ::: "memory");
    __builtin_amdgcn_s_barrier();
    __builtin_amdgcn_sched_barrier(0);
  }

  // ---- Epilogue PV[63] (trailing tile of the pipeline)
  {
    f16x8 pb0 = *(const f16x8*)&Psh[qg][l15][g * 8];
    f16x8 pb1 = *(const f16x8*)&Psh[qg][16 + l15][g * 8];
    __builtin_amdgcn_s_setprio(1);
    #pragma unroll
    for (int dt = 0; dt < 10; ++dt) {
      if (dt < ndt) {
        f16x8 vf = *(const f16x8*)&VTsh[(dtoff + dt) * 16 + l15][g * 8];
        O[dt][0] = __builtin_amdgcn_mfma_f32_16x16x32_f16(vf, pb0, O[dt][0], 0, 0, 0);
        O[dt][1] = __builtin_amdgcn_mfma_f32_16x16x32_f16(vf, pb1, O[dt][1], 0, 0, 0);
      }
    }
    __builtin_amdgcn_s_setprio(0);
  }

  // ---- combine pair half-sums, multiply by input row, store
  if (g == 0) Mx[qg][mem][l15] = float2{l0, l1};
  asm volatile("s_waitcnt lgkmcnt(0)" ::: "memory");
  __builtin_amdgcn_s_barrier();
  __builtin_amdgcn_sched_barrier(0);
  float2 pl = Mx[qg][mem ^ 1][l15];
  float r0 = 1.0f / (l0 + pl.x);
  float r1 = 1.0f / (l1 + pl.y);

  #pragma unroll
  for (int qi = 0; qi < 2; ++qi) {
    float rinv = qi ? r1 : r0;
    int q = qbase + qi * 16 + l15;
    const f16* mrow = Qsrc + bq + (size_t)q * DPK;
    size_t orow = (size_t)b * (4096 * 300) + (size_t)(dir * 2048 + q) * 300;
    #pragma unroll
    for (int dt = 0; dt < 10; ++dt) {
      if (dt < ndt) {
        int d = (dtoff + dt) * 16 + g * 4;
        if (d < 300) {
          f16x4 mu = *(const f16x4*)(mrow + d);
          f32x4 o;
          o[0] = O[dt][qi][0] * rinv * (float)mu[0];
          o[1] = O[dt][qi][1] * rinv * (float)mu[1];
          o[2] = O[dt][qi][2] * rinv * (float)mu[2];
          o[3] = O[dt][qi][3] * rinv * (float)mu[3];
          *(f32x4*)&out[orow + d] = o;
        }
      }
    }
  }
}

extern "C" void kernel_launch(void* const* d_in, const int* in_sizes, int n_in,
                              void* d_out, int out_size, void* d_ws, size_t ws_size,
                              hipStream_t stream) {
  const float* X = (const float*)d_in[0];
  const float* Y = (const float*)d_in[1];
  float* out = (float*)d_out;

  size_t need = (size_t)(2 * XF_ELEMS + 2 * XT_ELEMS) * sizeof(f16);  // ~83 MB
  if (ws_size < need) return;

  f16* Xf = (f16*)d_ws;
  f16* Yf = Xf + XF_ELEMS;
  f16* XT = Yf + XF_ELEMS;
  f16* YT = XT + XT_ELEMS;

  prep_kernel<<<dim3(65, 11, 32), 256, 0, stream>>>(X, Y, Xf, Yf, XT, YT);
  attn_kernel<<<dim3(512), 512, 0, stream>>>(Xf, Yf, XT, YT, out);
}